// Round 1
// baseline (480.921 us; speedup 1.0000x reference)
//
#include <hip/hip_runtime.h>
#include <hip/hip_bf16.h>
#include <math.h>
#include <type_traits>

using s16x8 = __attribute__((ext_vector_type(8))) short;
using s16x4 = __attribute__((ext_vector_type(4))) short;
using f32x4 = __attribute__((ext_vector_type(4))) float;

static __device__ __forceinline__ short f2bf(float f) {
  union { float f; unsigned u; } v; v.f = f;
  unsigned r = v.u + 0x7fff + ((v.u >> 16) & 1);   // RNE
  return (short)(r >> 16);
}

// ---------------- cast f32 -> bf16 (vectorized) ----------------
__global__ void cast_f32_bf16(const float* __restrict__ in, short* __restrict__ out, int n4) {
  int i = blockIdx.x * blockDim.x + threadIdx.x;
  int stride = gridDim.x * blockDim.x;
  for (int idx = i; idx < n4; idx += stride) {
    float4 v = reinterpret_cast<const float4*>(in)[idx];
    s16x4 o; o[0] = f2bf(v.x); o[1] = f2bf(v.y); o[2] = f2bf(v.z); o[3] = f2bf(v.w);
    reinterpret_cast<s16x4*>(out)[idx] = o;
  }
}

// ---------------- transpose + cast: in[R][C] f32 -> out[C][R] bf16 ----------------
__global__ void transpose_cast(const float* __restrict__ in, short* __restrict__ out, int R, int C) {
  __shared__ float tile[32][33];
  int cb = blockIdx.x * 32, rb = blockIdx.y * 32;
  int tx = threadIdx.x, ty = threadIdx.y;  // block (32, 8)
  #pragma unroll
  for (int i = 0; i < 32; i += 8)
    tile[ty + i][tx] = in[(size_t)(rb + ty + i) * C + cb + tx];
  __syncthreads();
  #pragma unroll
  for (int i = 0; i < 32; i += 8)
    out[(size_t)(cb + ty + i) * R + rb + tx] = f2bf(tile[tx][ty + i]);
}

// ---------------- bf16 MFMA GEMM: C[M][N] = A[M][K] * BT[N][K]^T ----------------
template <typename OutT>
__global__ __launch_bounds__(256) void gemm_bt(const short* __restrict__ A,
                                               const short* __restrict__ BT,
                                               OutT* __restrict__ C,
                                               int M, int N, int K) {
  __shared__ short As[128][32];
  __shared__ short Bs[128][32];
  const int t = threadIdx.x;
  const int lane = t & 63, wid = t >> 6;
  const int wm = wid >> 1, wn = wid & 1;           // 2x2 waves, 64x64 each
  const int bm = blockIdx.y * 128, bn = blockIdx.x * 128;
  const int lr = lane & 15, lg = lane >> 4;

  f32x4 acc[4][4] = {};

  for (int k0 = 0; k0 < K; k0 += 32) {
    #pragma unroll
    for (int c = 0; c < 2; ++c) {
      int chunk = c * 256 + t;               // 0..511
      int row = chunk >> 2, col8 = (chunk & 3) * 8;
      *reinterpret_cast<s16x8*>(&As[row][col8]) =
          *reinterpret_cast<const s16x8*>(&A[(size_t)(bm + row) * K + k0 + col8]);
      *reinterpret_cast<s16x8*>(&Bs[row][col8]) =
          *reinterpret_cast<const s16x8*>(&BT[(size_t)(bn + row) * K + k0 + col8]);
    }
    __syncthreads();
    s16x8 af[4], bfr[4];
    #pragma unroll
    for (int i = 0; i < 4; ++i)
      af[i] = *reinterpret_cast<s16x8*>(&As[wm * 64 + i * 16 + lr][lg * 8]);
    #pragma unroll
    for (int j = 0; j < 4; ++j)
      bfr[j] = *reinterpret_cast<s16x8*>(&Bs[wn * 64 + j * 16 + lr][lg * 8]);
    #pragma unroll
    for (int i = 0; i < 4; ++i)
      #pragma unroll
      for (int j = 0; j < 4; ++j)
        acc[i][j] = __builtin_amdgcn_mfma_f32_16x16x32_bf16(af[i], bfr[j], acc[i][j], 0, 0, 0);
    __syncthreads();
  }

  const int r0 = bm + wm * 64, c0 = bn + wn * 64;
  #pragma unroll
  for (int i = 0; i < 4; ++i)
    #pragma unroll
    for (int j = 0; j < 4; ++j)
      #pragma unroll
      for (int r = 0; r < 4; ++r) {
        int row = r0 + i * 16 + lg * 4 + r;
        int col = c0 + j * 16 + lr;
        float v = acc[i][j][r];
        if constexpr (std::is_same<OutT, short>::value)
          C[(size_t)row * N + col] = f2bf(v);
        else
          C[(size_t)row * N + col] = v;
      }
}

// ---------------- flash attention: 1 wave per 16-row Q block ----------------
// qkv: [B*T][3072] bf16 (q | k | v), att out: [B*T][1024] bf16
__global__ __launch_bounds__(64) void attn_kernel(const short* __restrict__ qkv,
                                                  short* __restrict__ att) {
  const int T = 2048, D = 64, C3 = 3072, Cc = 1024;
  const int qb = blockIdx.x, h = blockIdx.y, b = blockIdx.z;
  const int lane = threadIdx.x;
  const int lr = lane & 15, lg = lane >> 4;

  __shared__ short Plds[16][32];

  // Q fragments: A-layout, rows qb*16+lr, k = d
  s16x8 aq[2];
  #pragma unroll
  for (int c = 0; c < 2; ++c)
    aq[c] = *reinterpret_cast<const s16x8*>(
        qkv + (size_t)(b * T + qb * 16 + lr) * C3 + h * D + c * 32 + lg * 8);

  f32x4 o[4] = {};
  float mstate[4], lstate[4];
  #pragma unroll
  for (int r = 0; r < 4; ++r) { mstate[r] = -INFINITY; lstate[r] = 0.f; }

  const int qhi = qb * 16 + 15;
  for (int j0 = 0; j0 <= qhi; j0 += 32) {
    // scores: 2 ntiles of 16 keys, K-dim = D = 64 via 2 MFMAs each
    f32x4 st[2];
    #pragma unroll
    for (int tn = 0; tn < 2; ++tn) {
      f32x4 s = {};
      #pragma unroll
      for (int c = 0; c < 2; ++c) {
        s16x8 bk = *reinterpret_cast<const s16x8*>(
            qkv + (size_t)(b * T + j0 + tn * 16 + lr) * C3 + Cc + h * D + c * 32 + lg * 8);
        s = __builtin_amdgcn_mfma_f32_16x16x32_bf16(aq[c], bk, s, 0, 0, 0);
      }
      st[tn] = s;
    }
    // scale + causal mask + row max (rows live in 16-lane groups)
    float corr[4];
    #pragma unroll
    for (int r = 0; r < 4; ++r) {
      int qrow = qb * 16 + lg * 4 + r;
      #pragma unroll
      for (int tn = 0; tn < 2; ++tn) {
        int key = j0 + tn * 16 + lr;
        float v = st[tn][r] * 0.125f;
        st[tn][r] = (key <= qrow) ? v : -INFINITY;
      }
      float mx = fmaxf(st[0][r], st[1][r]);
      #pragma unroll
      for (int m = 1; m < 16; m <<= 1) mx = fmaxf(mx, __shfl_xor(mx, m));
      float mn = fmaxf(mstate[r], mx);
      corr[r] = expf(mstate[r] - mn);     // first iter: exp(-inf)=0
      mstate[r] = mn;
      float psum = 0.f;
      #pragma unroll
      for (int tn = 0; tn < 2; ++tn) {
        float p = expf(st[tn][r] - mn);   // masked: exp(-inf)=0
        st[tn][r] = p;
        psum += p;
      }
      #pragma unroll
      for (int m = 1; m < 16; m <<= 1) psum += __shfl_xor(psum, m);
      lstate[r] = lstate[r] * corr[r] + psum;
      #pragma unroll
      for (int cc = 0; cc < 4; ++cc) o[cc][r] *= corr[r];
    }
    // P -> LDS (re-fragment for PV A-operand)
    __syncthreads();
    #pragma unroll
    for (int r = 0; r < 4; ++r)
      #pragma unroll
      for (int tn = 0; tn < 2; ++tn)
        Plds[lg * 4 + r][tn * 16 + lr] = f2bf(st[tn][r]);
    __syncthreads();
    s16x8 pa = *reinterpret_cast<s16x8*>(&Plds[lr][lg * 8]);
    // PV: B = V[32 keys][16-col chunk], scalar gathers (optimize later)
    #pragma unroll
    for (int cc = 0; cc < 4; ++cc) {
      s16x8 bv;
      #pragma unroll
      for (int jj = 0; jj < 8; ++jj) {
        int key = j0 + lg * 8 + jj;
        bv[jj] = qkv[(size_t)(b * T + key) * C3 + 2 * Cc + h * D + cc * 16 + lr];
      }
      o[cc] = __builtin_amdgcn_mfma_f32_16x16x32_bf16(pa, bv, o[cc], 0, 0, 0);
    }
  }
  // epilogue: normalize and store att (bf16)
  #pragma unroll
  for (int cc = 0; cc < 4; ++cc)
    #pragma unroll
    for (int r = 0; r < 4; ++r) {
      int row = qb * 16 + lg * 4 + r;
      int col = h * D + cc * 16 + lr;
      att[(size_t)(b * T + row) * Cc + col] = f2bf(o[cc][r] / lstate[r]);
    }
}

extern "C" void kernel_launch(void* const* d_in, const int* in_sizes, int n_in,
                              void* d_out, int out_size, void* d_ws, size_t ws_size,
                              hipStream_t stream) {
  const float* x     = (const float*)d_in[0];   // [4,2048,1024]
  const float* w_qkv = (const float*)d_in[1];   // [1024,3072]
  const float* w_out = (const float*)d_in[2];   // [1024,1024]
  float* out = (float*)d_out;                   // [4,2048,1024]

  char* ws = (char*)d_ws;
  short* xb    = (short*)(ws);                        // 8192*1024*2   = 16,777,216
  short* wqkvT = (short*)(ws + 16777216);             // 3072*1024*2   =  6,291,456
  short* woT   = (short*)(ws + 16777216 + 6291456);   // 1024*1024*2   =  2,097,152
  short* qkv   = (short*)(ws + 25165824);             // 8192*3072*2   = 50,331,648
  short* att   = (short*)(ws + 75497472);             // 8192*1024*2   = 16,777,216
  // total ws use: 92,274,688 bytes

  cast_f32_bf16<<<2048, 256, 0, stream>>>(x, xb, (8192 * 1024) / 4);
  transpose_cast<<<dim3(3072 / 32, 1024 / 32), dim3(32, 8), 0, stream>>>(w_qkv, wqkvT, 1024, 3072);
  transpose_cast<<<dim3(1024 / 32, 1024 / 32), dim3(32, 8), 0, stream>>>(w_out, woT, 1024, 1024);

  gemm_bt<short><<<dim3(3072 / 128, 8192 / 128), 256, 0, stream>>>(xb, wqkvT, qkv, 8192, 3072, 1024);
  attn_kernel<<<dim3(2048 / 16, 16, 4), 64, 0, stream>>>(qkv, att);
  gemm_bt<float><<<dim3(1024 / 128, 8192 / 128), 256, 0, stream>>>(att, woT, out, 8192, 1024, 1024);
}

// Round 2
// 375.669 us; speedup vs baseline: 1.2802x; 1.2802x over previous
//
#include <hip/hip_runtime.h>
#include <hip/hip_bf16.h>
#include <math.h>
#include <type_traits>

using s16x8 = __attribute__((ext_vector_type(8))) short;
using s16x4 = __attribute__((ext_vector_type(4))) short;
using f32x4 = __attribute__((ext_vector_type(4))) float;

static __device__ __forceinline__ short f2bf(float f) {
  union { float f; unsigned u; } v; v.f = f;
  unsigned r = v.u + 0x7fff + ((v.u >> 16) & 1);   // RNE
  return (short)(r >> 16);
}

#define GLOAD_LDS(gsrc, ldst)                                                      \
  __builtin_amdgcn_global_load_lds(                                                \
      (const __attribute__((address_space(1))) void*)(gsrc),                       \
      (__attribute__((address_space(3))) void*)(ldst), 16, 0, 0)

// ---------------- cast f32 -> bf16 (vectorized) ----------------
__global__ void cast_f32_bf16(const float* __restrict__ in, short* __restrict__ out, int n4) {
  int i = blockIdx.x * blockDim.x + threadIdx.x;
  int stride = gridDim.x * blockDim.x;
  for (int idx = i; idx < n4; idx += stride) {
    float4 v = reinterpret_cast<const float4*>(in)[idx];
    s16x4 o; o[0] = f2bf(v.x); o[1] = f2bf(v.y); o[2] = f2bf(v.z); o[3] = f2bf(v.w);
    reinterpret_cast<s16x4*>(out)[idx] = o;
  }
}

// ---------------- transpose + cast: in[R][C] f32 -> out[C][R] bf16 ----------------
__global__ void transpose_cast(const float* __restrict__ in, short* __restrict__ out, int R, int C) {
  __shared__ float tile[32][33];
  int cb = blockIdx.x * 32, rb = blockIdx.y * 32;
  int tx = threadIdx.x, ty = threadIdx.y;  // block (32, 8)
  #pragma unroll
  for (int i = 0; i < 32; i += 8)
    tile[ty + i][tx] = in[(size_t)(rb + ty + i) * C + cb + tx];
  __syncthreads();
  #pragma unroll
  for (int i = 0; i < 32; i += 8)
    out[(size_t)(cb + ty + i) * R + rb + tx] = f2bf(tile[tx][ty + i]);
}

// ---------------- transpose V out of qkv: vt[(b*16+h)*64 + d][T] ----------------
__global__ void transpose_v(const short* __restrict__ qkv, short* __restrict__ vt) {
  const int T = 2048, C3 = 3072;
  __shared__ short tile[32][33];
  int tb = blockIdx.x * 32;         // token base
  int db = blockIdx.y * 32;         // d base (0 or 32)
  int bh = blockIdx.z;              // b*16+h
  int b = bh >> 4, h = bh & 15;
  int tx = threadIdx.x, ty = threadIdx.y;  // block (32, 8)
  #pragma unroll
  for (int i = 0; i < 32; i += 8)
    tile[ty + i][tx] = qkv[(size_t)(b * T + tb + ty + i) * C3 + 2048 + h * 64 + db + tx];
  __syncthreads();
  #pragma unroll
  for (int i = 0; i < 32; i += 8)
    vt[(size_t)(bh * 64 + db + ty + i) * T + tb + tx] = tile[tx][ty + i];
}

// ---------------- bf16 MFMA GEMM: C[M][N] = A[M][K] * BT[N][K]^T ----------------
template <typename OutT>
__global__ __launch_bounds__(256) void gemm_bt(const short* __restrict__ A,
                                               const short* __restrict__ BT,
                                               OutT* __restrict__ C,
                                               int M, int N, int K) {
  __shared__ __align__(16) short As[128][32];
  __shared__ __align__(16) short Bs[128][32];
  const int t = threadIdx.x;
  const int lane = t & 63, wid = t >> 6;
  const int wm = wid >> 1, wn = wid & 1;           // 2x2 waves, 64x64 each
  const int bm = blockIdx.y * 128, bn = blockIdx.x * 128;
  const int lr = lane & 15, lg = lane >> 4;

  f32x4 acc[4][4] = {};

  for (int k0 = 0; k0 < K; k0 += 32) {
    // stage via global_load_lds, width 16; layout = linear row-major [128][32]
    #pragma unroll
    for (int rnd = 0; rnd < 2; ++rnd) {
      int chunk = rnd * 256 + t;               // 0..511, 16B chunks
      int row = chunk >> 2, c8 = (chunk & 3) * 8;
      GLOAD_LDS(&A[(size_t)(bm + row) * K + k0 + c8], &As[rnd * 64 + wid * 16][0]);
      GLOAD_LDS(&BT[(size_t)(bn + row) * K + k0 + c8], &Bs[rnd * 64 + wid * 16][0]);
    }
    __syncthreads();
    s16x8 af[4], bfr[4];
    #pragma unroll
    for (int i = 0; i < 4; ++i)
      af[i] = *reinterpret_cast<s16x8*>(&As[wm * 64 + i * 16 + lr][lg * 8]);
    #pragma unroll
    for (int j = 0; j < 4; ++j)
      bfr[j] = *reinterpret_cast<s16x8*>(&Bs[wn * 64 + j * 16 + lr][lg * 8]);
    #pragma unroll
    for (int i = 0; i < 4; ++i)
      #pragma unroll
      for (int j = 0; j < 4; ++j)
        acc[i][j] = __builtin_amdgcn_mfma_f32_16x16x32_bf16(af[i], bfr[j], acc[i][j], 0, 0, 0);
    __syncthreads();
  }

  const int r0 = bm + wm * 64, c0 = bn + wn * 64;
  #pragma unroll
  for (int i = 0; i < 4; ++i)
    #pragma unroll
    for (int j = 0; j < 4; ++j)
      #pragma unroll
      for (int r = 0; r < 4; ++r) {
        int row = r0 + i * 16 + lg * 4 + r;
        int col = c0 + j * 16 + lr;
        float v = acc[i][j][r];
        if constexpr (std::is_same<OutT, short>::value)
          C[(size_t)row * N + col] = f2bf(v);
        else
          C[(size_t)row * N + col] = v;
      }
}

// ---------------- flash attention: 4 waves/block, QBLK=64, KVBLK=64 ----------------
// qkv: [B*T][3072] bf16 (q|k|v); vt: [(b*16+h)*64 + d][2048] bf16; att: [B*T][1024]
__global__ __launch_bounds__(256) void attn_kernel(const short* __restrict__ qkv,
                                                   const short* __restrict__ vt,
                                                   short* __restrict__ att) {
  const int T = 2048, C3 = 3072, Cc = 1024;
  const int qb = blockIdx.x, h = blockIdx.y, b = blockIdx.z;
  const int bh = b * 16 + h;
  const int t = threadIdx.x;
  const int w = t >> 6, l = t & 63;
  const int lr = l & 15, lg = l >> 4;

  // swizzled tiles: LDS(row, chunk) holds global chunk (chunk ^ (row&7)); chunks are 16B
  __shared__ __align__(16) short Ks[2][64 * 64];
  __shared__ __align__(16) short Vts[2][64 * 64];
  __shared__ __align__(16) short Plds[4][16 * 64];

  const int qrow_base = qb * 64 + w * 16;

  // Q fragments (A-operand): rows qrow_base+lr, k = d
  s16x8 aq[2];
  #pragma unroll
  for (int c = 0; c < 2; ++c)
    aq[c] = *reinterpret_cast<const s16x8*>(
        qkv + (size_t)(b * T + qrow_base + lr) * C3 + h * 64 + c * 32 + lg * 8);

  f32x4 o[4] = {};
  float mst[4], lst[4];
  #pragma unroll
  for (int r = 0; r < 4; ++r) { mst[r] = -INFINITY; lst[r] = 0.f; }

  const float SC = 0.125f * 1.44269504088896340736f;  // scale * log2(e); softmax in exp2 domain
  const int nt = qb + 1;

  // stage one 64-key tile: K rows [key][d], Vt rows [d][key]; wave w covers rows w*16..w*16+15
  auto stage = [&](int buf, int j0) {
    #pragma unroll
    for (int i = 0; i < 2; ++i) {
      int row = w * 16 + i * 8 + (l >> 3);            // row&7 == l>>3
      int srcc = (l & 7) ^ (l >> 3);                  // pre-swizzled source chunk
      GLOAD_LDS(qkv + (size_t)(b * T + j0 + row) * C3 + Cc + h * 64 + srcc * 8,
                &Ks[buf][(w * 16 + i * 8) * 64]);
      GLOAD_LDS(vt + (size_t)(bh * 64 + row) * T + j0 + srcc * 8,
                &Vts[buf][(w * 16 + i * 8) * 64]);
    }
  };

  stage(0, 0);
  for (int tt = 0; tt < nt; ++tt) {
    __syncthreads();                      // drains vmcnt: buf[tt&1] ready; prev reads done
    if (tt + 1 < nt) stage((tt + 1) & 1, (tt + 1) * 64);
    const int cur = tt & 1;
    const int j0 = tt * 64;
    const short* K_ = Ks[cur];
    const short* V_ = Vts[cur];

    // ---- QK^T: S[16 q][64 keys] ----
    f32x4 st[4];
    #pragma unroll
    for (int tn = 0; tn < 4; ++tn) {
      f32x4 s = {};
      #pragma unroll
      for (int c = 0; c < 2; ++c) {
        s16x8 bk = *reinterpret_cast<const s16x8*>(
            &K_[(tn * 16 + lr) * 64 + (((c * 4 + lg) ^ (lr & 7)) * 8)]);
        s = __builtin_amdgcn_mfma_f32_16x16x32_bf16(aq[c], bk, s, 0, 0, 0);
      }
      st[tn] = s;
    }

    const bool needmask = (j0 + 64 > qrow_base);   // only the diagonal tile
    float corr[4];
    #pragma unroll
    for (int r = 0; r < 4; ++r) {
      const int qrow = qrow_base + lg * 4 + r;
      float mx = -INFINITY;
      #pragma unroll
      for (int tn = 0; tn < 4; ++tn) {
        float v = st[tn][r] * SC;
        if (needmask && (j0 + tn * 16 + lr > qrow)) v = -INFINITY;
        st[tn][r] = v;
        mx = fmaxf(mx, v);
      }
      #pragma unroll
      for (int m = 1; m < 16; m <<= 1) mx = fmaxf(mx, __shfl_xor(mx, m));
      float mn = fmaxf(mst[r], mx);
      corr[r] = exp2f(mst[r] - mn);
      mst[r] = mn;
      float ps = 0.f;
      #pragma unroll
      for (int tn = 0; tn < 4; ++tn) {
        float p = exp2f(st[tn][r] - mn);
        st[tn][r] = p;
        ps += p;
      }
      #pragma unroll
      for (int m = 1; m < 16; m <<= 1) ps += __shfl_xor(ps, m);
      lst[r] = lst[r] * corr[r] + ps;
      #pragma unroll
      for (int cc = 0; cc < 4; ++cc) o[cc][r] *= corr[r];
    }

    // ---- P -> LDS (wave-private, swizzled) ----
    #pragma unroll
    for (int r = 0; r < 4; ++r) {
      int row = lg * 4 + r;
      #pragma unroll
      for (int tn = 0; tn < 4; ++tn) {
        int col = tn * 16 + lr;
        int swc = (col >> 3) ^ (row & 7);
        Plds[w][row * 64 + swc * 8 + (col & 7)] = f2bf(st[tn][r]);
      }
    }
    s16x8 pa[2];
    #pragma unroll
    for (int ks = 0; ks < 2; ++ks)
      pa[ks] = *reinterpret_cast<s16x8*>(
          &Plds[w][lr * 64 + (((ks * 4 + lg) ^ (lr & 7)) * 8)]);

    // ---- PV ----
    #pragma unroll
    for (int cc = 0; cc < 4; ++cc)
      #pragma unroll
      for (int ks = 0; ks < 2; ++ks) {
        s16x8 bv = *reinterpret_cast<const s16x8*>(
            &V_[(cc * 16 + lr) * 64 + (((ks * 4 + lg) ^ (lr & 7)) * 8)]);
        o[cc] = __builtin_amdgcn_mfma_f32_16x16x32_bf16(pa[ks], bv, o[cc], 0, 0, 0);
      }
  }

  // ---- epilogue ----
  #pragma unroll
  for (int cc = 0; cc < 4; ++cc)
    #pragma unroll
    for (int r = 0; r < 4; ++r) {
      int row = qrow_base + lg * 4 + r;
      att[(size_t)(b * T + row) * Cc + h * 64 + cc * 16 + lr] = f2bf(o[cc][r] / lst[r]);
    }
}

extern "C" void kernel_launch(void* const* d_in, const int* in_sizes, int n_in,
                              void* d_out, int out_size, void* d_ws, size_t ws_size,
                              hipStream_t stream) {
  const float* x     = (const float*)d_in[0];   // [4,2048,1024]
  const float* w_qkv = (const float*)d_in[1];   // [1024,3072]
  const float* w_out = (const float*)d_in[2];   // [1024,1024]
  float* out = (float*)d_out;                   // [4,2048,1024]

  char* ws = (char*)d_ws;
  short* xb    = (short*)(ws);                        // 16,777,216 B (dead after gemm1)
  short* vtb   = (short*)(ws);                        // aliases xb: written after gemm1
  short* wqkvT = (short*)(ws + 16777216);             // 6,291,456
  short* woT   = (short*)(ws + 23068672);             // 2,097,152
  short* qkv   = (short*)(ws + 25165824);             // 50,331,648
  short* att   = (short*)(ws + 75497472);             // 16,777,216  -> total 92.3 MB

  cast_f32_bf16<<<2048, 256, 0, stream>>>(x, xb, (8192 * 1024) / 4);
  transpose_cast<<<dim3(3072 / 32, 1024 / 32), dim3(32, 8), 0, stream>>>(w_qkv, wqkvT, 1024, 3072);
  transpose_cast<<<dim3(1024 / 32, 1024 / 32), dim3(32, 8), 0, stream>>>(w_out, woT, 1024, 1024);

  gemm_bt<short><<<dim3(3072 / 128, 8192 / 128), 256, 0, stream>>>(xb, wqkvT, qkv, 8192, 3072, 1024);
  transpose_v<<<dim3(2048 / 32, 2, 64), dim3(32, 8), 0, stream>>>(qkv, vtb);
  attn_kernel<<<dim3(2048 / 64, 16, 4), 256, 0, stream>>>(qkv, vtb, att);
  gemm_bt<float><<<dim3(1024 / 128, 8192 / 128), 256, 0, stream>>>(att, woT, out, 8192, 1024, 1024);
}

// Round 3
// 287.080 us; speedup vs baseline: 1.6752x; 1.3086x over previous
//
#include <hip/hip_runtime.h>
#include <hip/hip_bf16.h>
#include <math.h>
#include <type_traits>

using s16x8 = __attribute__((ext_vector_type(8))) short;
using s16x4 = __attribute__((ext_vector_type(4))) short;
using f32x4 = __attribute__((ext_vector_type(4))) float;
using f32x16 = __attribute__((ext_vector_type(16))) float;
using u32 = unsigned int;
using u32x4 = __attribute__((ext_vector_type(4))) u32;

static __device__ __forceinline__ short f2bf(float f) {
  union { float f; unsigned u; } v; v.f = f;
  unsigned r = v.u + 0x7fff + ((v.u >> 16) & 1);   // RNE
  return (short)(r >> 16);
}

static __device__ __forceinline__ unsigned cvt_pk_bf16(float lo, float hi) {
  unsigned r;
  asm("v_cvt_pk_bf16_f32 %0, %1, %2" : "=v"(r) : "v"(lo), "v"(hi));
  return r;
}

#define GLOAD_LDS(gsrc, ldst)                                                      \
  __builtin_amdgcn_global_load_lds(                                                \
      (const __attribute__((address_space(1))) void*)(gsrc),                       \
      (__attribute__((address_space(3))) void*)(ldst), 16, 0, 0)

// ---------------- cast f32 -> bf16 (vectorized) ----------------
__global__ void cast_f32_bf16(const float* __restrict__ in, short* __restrict__ out, int n4) {
  int i = blockIdx.x * blockDim.x + threadIdx.x;
  int stride = gridDim.x * blockDim.x;
  for (int idx = i; idx < n4; idx += stride) {
    float4 v = reinterpret_cast<const float4*>(in)[idx];
    s16x4 o; o[0] = f2bf(v.x); o[1] = f2bf(v.y); o[2] = f2bf(v.z); o[3] = f2bf(v.w);
    reinterpret_cast<s16x4*>(out)[idx] = o;
  }
}

// ---------------- transpose + cast: in[R][C] f32 -> out[C][R] bf16 ----------------
__global__ void transpose_cast(const float* __restrict__ in, short* __restrict__ out, int R, int C) {
  __shared__ float tile[32][33];
  int cb = blockIdx.x * 32, rb = blockIdx.y * 32;
  int tx = threadIdx.x, ty = threadIdx.y;  // block (32, 8)
  #pragma unroll
  for (int i = 0; i < 32; i += 8)
    tile[ty + i][tx] = in[(size_t)(rb + ty + i) * C + cb + tx];
  __syncthreads();
  #pragma unroll
  for (int i = 0; i < 32; i += 8)
    out[(size_t)(cb + ty + i) * R + rb + tx] = f2bf(tile[tx][ty + i]);
}

// ---------------- transpose V out of qkv: vt[(b*16+h)*64 + d][T] ----------------
__global__ void transpose_v(const short* __restrict__ qkv, short* __restrict__ vt) {
  const int T = 2048, C3 = 3072;
  __shared__ short tile[32][33];
  int tb = blockIdx.x * 32;         // token base
  int db = blockIdx.y * 32;         // d base (0 or 32)
  int bh = blockIdx.z;              // b*16+h
  int b = bh >> 4, h = bh & 15;
  int tx = threadIdx.x, ty = threadIdx.y;  // block (32, 8)
  #pragma unroll
  for (int i = 0; i < 32; i += 8)
    tile[ty + i][tx] = qkv[(size_t)(b * T + tb + ty + i) * C3 + 2048 + h * 64 + db + tx];
  __syncthreads();
  #pragma unroll
  for (int i = 0; i < 32; i += 8)
    vt[(size_t)(bh * 64 + db + ty + i) * T + tb + tx] = tile[tx][ty + i];
}

// ---------------- bf16 MFMA GEMM: C[M][N] = A[M][K] * BT[N][K]^T ----------------
template <typename OutT>
__global__ __launch_bounds__(256) void gemm_bt(const short* __restrict__ A,
                                               const short* __restrict__ BT,
                                               OutT* __restrict__ C,
                                               int M, int N, int K) {
  __shared__ __align__(16) short As[128][32];
  __shared__ __align__(16) short Bs[128][32];
  const int t = threadIdx.x;
  const int lane = t & 63, wid = t >> 6;
  const int wm = wid >> 1, wn = wid & 1;           // 2x2 waves, 64x64 each
  const int bm = blockIdx.y * 128, bn = blockIdx.x * 128;
  const int lr = lane & 15, lg = lane >> 4;

  f32x4 acc[4][4] = {};

  for (int k0 = 0; k0 < K; k0 += 32) {
    #pragma unroll
    for (int rnd = 0; rnd < 2; ++rnd) {
      int chunk = rnd * 256 + t;               // 0..511, 16B chunks
      int row = chunk >> 2, c8 = (chunk & 3) * 8;
      GLOAD_LDS(&A[(size_t)(bm + row) * K + k0 + c8], &As[rnd * 64 + wid * 16][0]);
      GLOAD_LDS(&BT[(size_t)(bn + row) * K + k0 + c8], &Bs[rnd * 64 + wid * 16][0]);
    }
    __syncthreads();
    s16x8 af[4], bfr[4];
    #pragma unroll
    for (int i = 0; i < 4; ++i)
      af[i] = *reinterpret_cast<s16x8*>(&As[wm * 64 + i * 16 + lr][lg * 8]);
    #pragma unroll
    for (int j = 0; j < 4; ++j)
      bfr[j] = *reinterpret_cast<s16x8*>(&Bs[wn * 64 + j * 16 + lr][lg * 8]);
    #pragma unroll
    for (int i = 0; i < 4; ++i)
      #pragma unroll
      for (int j = 0; j < 4; ++j)
        acc[i][j] = __builtin_amdgcn_mfma_f32_16x16x32_bf16(af[i], bfr[j], acc[i][j], 0, 0, 0);
    __syncthreads();
  }

  const int r0 = bm + wm * 64, c0 = bn + wn * 64;
  #pragma unroll
  for (int i = 0; i < 4; ++i)
    #pragma unroll
    for (int j = 0; j < 4; ++j)
      #pragma unroll
      for (int r = 0; r < 4; ++r) {
        int row = r0 + i * 16 + lg * 4 + r;
        int col = c0 + j * 16 + lr;
        float v = acc[i][j][r];
        if constexpr (std::is_same<OutT, short>::value)
          C[(size_t)row * N + col] = f2bf(v);
        else
          C[(size_t)row * N + col] = v;
      }
}

// ---------------- flash attention: 4 waves x 32 q-rows, 32x32 MFMA, swapped operands ----
// qkv: [B*T][3072] bf16 (q|k|v); vt: [(b*16+h)*64 + d][2048]; att: [B*T][1024]
__global__ __launch_bounds__(256) void attn_kernel(const short* __restrict__ qkv,
                                                   const short* __restrict__ vt,
                                                   short* __restrict__ att) {
  const int T = 2048, C3 = 3072, Cc = 1024;
  const int fid = blockIdx.x;
  const int qb = 15 - (fid & 15);            // qb descending (LPT), bh-major for L2 reuse
  const int bh = fid >> 4;
  const int h = bh & 15, b = bh >> 4;
  const int t = threadIdx.x;
  const int w = t >> 6, l = t & 63;
  const int q2 = l & 31, hi = l >> 5;

  __shared__ __align__(16) short Ks[2][64 * 64];   // [key][d], chunk-swizzled
  __shared__ __align__(16) short Vts[2][64 * 64];  // [d][key], chunk-swizzled

  const int qrow_base = qb * 128 + w * 32;
  const int qrow = qrow_base + q2;

  // Q B-fragments (col=lane&31=q, k=d), pre-scaled by 0.125*log2(e)
  const float SC = 0.125f * 1.44269504088896340736f;
  s16x8 aq[4];
  #pragma unroll
  for (int ds = 0; ds < 4; ++ds) {
    s16x8 q = *reinterpret_cast<const s16x8*>(
        qkv + (size_t)(b * T + qrow) * C3 + h * 64 + ds * 16 + hi * 8);
    #pragma unroll
    for (int j = 0; j < 8; ++j) {
      union { float f; unsigned u; } v; v.u = ((unsigned)(unsigned short)q[j]) << 16;
      q[j] = f2bf(v.f * SC);
    }
    aq[ds] = q;
  }

  f32x16 o[2] = {};                  // O^T: [d][q], col=lane&31=q
  float mst = -INFINITY, lst = 0.f;  // scalar per lane (q = q2)

  const int nt = 2 * qb + 2;

  auto stage = [&](int buf, int j0) {
    #pragma unroll
    for (int i = 0; i < 2; ++i) {
      int row = w * 16 + i * 8 + (l >> 3);
      int srcc = (l & 7) ^ (l >> 3);
      GLOAD_LDS(qkv + (size_t)(b * T + j0 + row) * C3 + Cc + h * 64 + srcc * 8,
                &Ks[buf][(w * 16 + i * 8) * 64]);
      GLOAD_LDS(vt + (size_t)(bh * 64 + row) * T + j0 + srcc * 8,
                &Vts[buf][(w * 16 + i * 8) * 64]);
    }
  };

  stage(0, 0);
  for (int tt = 0; tt < nt; ++tt) {
    __syncthreads();
    if (tt + 1 < nt) stage((tt + 1) & 1, (tt + 1) * 64);
    const int j0 = tt * 64;
    if (j0 <= qrow_base + 31) {                 // else fully-masked for this wave
      const short* K_ = Ks[tt & 1];
      const short* V_ = Vts[tt & 1];

      // ---- swapped QK^T: S^T[key][q] ----
      f32x16 st[2];
      #pragma unroll
      for (int kt = 0; kt < 2; ++kt) {
        f32x16 s = {};
        #pragma unroll
        for (int ds = 0; ds < 4; ++ds) {
          int row = kt * 32 + q2;
          s16x8 ak = *reinterpret_cast<const s16x8*>(
              &K_[row * 64 + (((ds * 2 + hi) ^ (row & 7)) * 8)]);
          s = __builtin_amdgcn_mfma_f32_32x32x16_bf16(ak, aq[ds], s, 0, 0, 0);
        }
        st[kt] = s;
      }

      // ---- causal mask (diagonal tiles only) ----
      if (j0 + 63 > qrow_base) {
        #pragma unroll
        for (int kt = 0; kt < 2; ++kt)
          #pragma unroll
          for (int r = 0; r < 16; ++r) {
            int key = j0 + kt * 32 + (r & 3) + 8 * (r >> 2) + 4 * hi;
            if (key > qrow) st[kt][r] = -INFINITY;
          }
      }

      // ---- in-register softmax (exp2 domain) ----
      float a16[16];
      #pragma unroll
      for (int r = 0; r < 16; ++r) a16[r] = fmaxf(st[0][r], st[1][r]);
      #pragma unroll
      for (int r = 0; r < 8; ++r) a16[r] = fmaxf(a16[r], a16[r + 8]);
      #pragma unroll
      for (int r = 0; r < 4; ++r) a16[r] = fmaxf(a16[r], a16[r + 4]);
      float mx = fmaxf(fmaxf(a16[0], a16[1]), fmaxf(a16[2], a16[3]));
      mx = fmaxf(mx, __shfl_xor(mx, 32));
      float mn = fmaxf(mst, mx);
      float corr = exp2f(mst - mn);
      mst = mn;
      #pragma unroll
      for (int kt = 0; kt < 2; ++kt)
        #pragma unroll
        for (int r = 0; r < 16; ++r) st[kt][r] = exp2f(st[kt][r] - mn);
      float sv[16];
      #pragma unroll
      for (int r = 0; r < 16; ++r) sv[r] = st[0][r] + st[1][r];
      #pragma unroll
      for (int r = 0; r < 8; ++r) sv[r] += sv[r + 8];
      #pragma unroll
      for (int r = 0; r < 4; ++r) sv[r] += sv[r + 4];
      float ps = (sv[0] + sv[1]) + (sv[2] + sv[3]);
      ps += __shfl_xor(ps, 32);
      lst = lst * corr + ps;
      #pragma unroll
      for (int dt = 0; dt < 2; ++dt)
        #pragma unroll
        for (int r = 0; r < 16; ++r) o[dt][r] *= corr;

      // ---- repack P^T -> B-fragments (in-register, cvt_pk + shfl exchange) ----
      s16x8 pb[4];
      #pragma unroll
      for (int kt = 0; kt < 2; ++kt)
        #pragma unroll
        for (int s = 0; s < 2; ++s) {
          unsigned w01 = cvt_pk_bf16(st[kt][s * 8 + 0], st[kt][s * 8 + 1]);
          unsigned w23 = cvt_pk_bf16(st[kt][s * 8 + 2], st[kt][s * 8 + 3]);
          unsigned w45 = cvt_pk_bf16(st[kt][s * 8 + 4], st[kt][s * 8 + 5]);
          unsigned w67 = cvt_pk_bf16(st[kt][s * 8 + 6], st[kt][s * 8 + 7]);
          unsigned x01 = (unsigned)__shfl_xor((int)w01, 32);
          unsigned x23 = (unsigned)__shfl_xor((int)w23, 32);
          unsigned x45 = (unsigned)__shfl_xor((int)w45, 32);
          unsigned x67 = (unsigned)__shfl_xor((int)w67, 32);
          u32x4 f;
          f[0] = hi ? x45 : w01;
          f[1] = hi ? x67 : w23;
          f[2] = hi ? w45 : x01;
          f[3] = hi ? w67 : x23;
          pb[kt * 2 + s] = *reinterpret_cast<s16x8*>(&f);
        }

      // ---- swapped PV: O^T[d][q] += V^T[d][k] * P^T[k][q] ----
      #pragma unroll
      for (int dt = 0; dt < 2; ++dt) {
        int row = dt * 32 + q2;
        #pragma unroll
        for (int ks = 0; ks < 4; ++ks) {
          s16x8 av = *reinterpret_cast<const s16x8*>(
              &V_[row * 64 + (((ks * 2 + hi) ^ (row & 7)) * 8)]);
          o[dt] = __builtin_amdgcn_mfma_f32_32x32x16_bf16(av, pb[ks], o[dt], 0, 0, 0);
        }
      }
    }
  }

  // ---- epilogue: O^T -> att[token][C] via swizzled per-wave LDS transpose ----
  __syncthreads();
  u32* osm = reinterpret_cast<u32*>(&Ks[0][0]) + w * 1024;  // 4KB per wave
  float inv = 1.f / lst;
  #pragma unroll
  for (int dt = 0; dt < 2; ++dt)
    #pragma unroll
    for (int p = 0; p < 8; ++p) {
      unsigned pk = ((unsigned)(unsigned short)f2bf(o[dt][2 * p + 1] * inv) << 16)
                  | (unsigned)(unsigned short)f2bf(o[dt][2 * p] * inv);
      int col = dt * 16 + (p >> 1) * 4 + 2 * hi + (p & 1);   // u32 col = d/2
      int chunk = col >> 2, inc = col & 3;
      osm[q2 * 32 + ((chunk ^ (q2 & 7)) * 4) + inc] = pk;
    }
  __syncthreads();
  #pragma unroll
  for (int c = 0; c < 4; ++c) {
    int chunk = hi * 4 + c;
    u32x4 v4 = *reinterpret_cast<u32x4*>(&osm[q2 * 32 + ((chunk ^ (q2 & 7)) * 4)]);
    *reinterpret_cast<u32x4*>(
        att + (size_t)(b * T + qrow_base + q2) * Cc + h * 64 + chunk * 8) = v4;
  }
}

extern "C" void kernel_launch(void* const* d_in, const int* in_sizes, int n_in,
                              void* d_out, int out_size, void* d_ws, size_t ws_size,
                              hipStream_t stream) {
  const float* x     = (const float*)d_in[0];   // [4,2048,1024]
  const float* w_qkv = (const float*)d_in[1];   // [1024,3072]
  const float* w_out = (const float*)d_in[2];   // [1024,1024]
  float* out = (float*)d_out;                   // [4,2048,1024]

  char* ws = (char*)d_ws;
  short* xb    = (short*)(ws);                        // 16,777,216 B (dead after gemm1)
  short* vtb   = (short*)(ws);                        // aliases xb: written after gemm1
  short* wqkvT = (short*)(ws + 16777216);             // 6,291,456
  short* woT   = (short*)(ws + 23068672);             // 2,097,152
  short* qkv   = (short*)(ws + 25165824);             // 50,331,648
  short* att   = (short*)(ws + 75497472);             // 16,777,216  -> total 92.3 MB

  cast_f32_bf16<<<2048, 256, 0, stream>>>(x, xb, (8192 * 1024) / 4);
  transpose_cast<<<dim3(3072 / 32, 1024 / 32), dim3(32, 8), 0, stream>>>(w_qkv, wqkvT, 1024, 3072);
  transpose_cast<<<dim3(1024 / 32, 1024 / 32), dim3(32, 8), 0, stream>>>(w_out, woT, 1024, 1024);

  gemm_bt<short><<<dim3(3072 / 128, 8192 / 128), 256, 0, stream>>>(xb, wqkvT, qkv, 8192, 3072, 1024);
  transpose_v<<<dim3(2048 / 32, 2, 64), dim3(32, 8), 0, stream>>>(qkv, vtb);
  attn_kernel<<<1024, 256, 0, stream>>>(qkv, vtb, att);
  gemm_bt<float><<<dim3(1024 / 128, 8192 / 128), 256, 0, stream>>>(att, woT, out, 8192, 1024, 1024);
}

// Round 4
// 210.352 us; speedup vs baseline: 2.2863x; 1.3648x over previous
//
#include <hip/hip_runtime.h>
#include <hip/hip_bf16.h>
#include <math.h>
#include <type_traits>

using s16x8 = __attribute__((ext_vector_type(8))) short;
using s16x4 = __attribute__((ext_vector_type(4))) short;
using f32x4 = __attribute__((ext_vector_type(4))) float;
using f32x16 = __attribute__((ext_vector_type(16))) float;
using u32 = unsigned int;
using u32x4 = __attribute__((ext_vector_type(4))) u32;

static __device__ __forceinline__ short f2bf(float f) {
  union { float f; unsigned u; } v; v.f = f;
  unsigned r = v.u + 0x7fff + ((v.u >> 16) & 1);   // RNE
  return (short)(r >> 16);
}

static __device__ __forceinline__ unsigned cvt_pk_bf16(float lo, float hi) {
  unsigned r;
  asm("v_cvt_pk_bf16_f32 %0, %1, %2" : "=v"(r) : "v"(lo), "v"(hi));
  return r;
}

#define GLOAD_LDS(gsrc, ldst)                                                      \
  __builtin_amdgcn_global_load_lds(                                                \
      (const __attribute__((address_space(1))) void*)(gsrc),                       \
      (__attribute__((address_space(3))) void*)(ldst), 16, 0, 0)

// ---------------- cast f32 -> bf16 (vectorized) ----------------
__global__ void cast_f32_bf16(const float* __restrict__ in, short* __restrict__ out, int n4) {
  int i = blockIdx.x * blockDim.x + threadIdx.x;
  int stride = gridDim.x * blockDim.x;
  for (int idx = i; idx < n4; idx += stride) {
    float4 v = reinterpret_cast<const float4*>(in)[idx];
    s16x4 o; o[0] = f2bf(v.x); o[1] = f2bf(v.y); o[2] = f2bf(v.z); o[3] = f2bf(v.w);
    reinterpret_cast<s16x4*>(out)[idx] = o;
  }
}

// ---------------- transpose + cast: in[R][C] f32 -> out[C][R] bf16 ----------------
__global__ void transpose_cast(const float* __restrict__ in, short* __restrict__ out, int R, int C) {
  __shared__ float tile[32][33];
  int cb = blockIdx.x * 32, rb = blockIdx.y * 32;
  int tx = threadIdx.x, ty = threadIdx.y;  // block (32, 8)
  #pragma unroll
  for (int i = 0; i < 32; i += 8)
    tile[ty + i][tx] = in[(size_t)(rb + ty + i) * C + cb + tx];
  __syncthreads();
  #pragma unroll
  for (int i = 0; i < 32; i += 8)
    out[(size_t)(cb + ty + i) * R + rb + tx] = f2bf(tile[tx][ty + i]);
}

// ---------------- transpose V out of qkv: vt[(b*16+h)*64 + d][T] ----------------
__global__ void transpose_v(const short* __restrict__ qkv, short* __restrict__ vt) {
  const int T = 2048, C3 = 3072;
  __shared__ short tile[32][33];
  int tb = blockIdx.x * 32;         // token base
  int db = blockIdx.y * 32;         // d base (0 or 32)
  int bh = blockIdx.z;              // b*16+h
  int b = bh >> 4, h = bh & 15;
  int tx = threadIdx.x, ty = threadIdx.y;  // block (32, 8)
  #pragma unroll
  for (int i = 0; i < 32; i += 8)
    tile[ty + i][tx] = qkv[(size_t)(b * T + tb + ty + i) * C3 + 2048 + h * 64 + db + tx];
  __syncthreads();
  #pragma unroll
  for (int i = 0; i < 32; i += 8)
    vt[(size_t)(bh * 64 + db + ty + i) * T + tb + tx] = tile[tx][ty + i];
}

// ---------------- bf16 MFMA GEMM: C[M][N] = A[M][K] * BT[N][K]^T ----------------
template <typename OutT>
__global__ __launch_bounds__(256) void gemm_bt(const short* __restrict__ A,
                                               const short* __restrict__ BT,
                                               OutT* __restrict__ C,
                                               int M, int N, int K) {
  __shared__ __align__(16) short As[128][32];
  __shared__ __align__(16) short Bs[128][32];
  const int t = threadIdx.x;
  const int lane = t & 63, wid = t >> 6;
  const int wm = wid >> 1, wn = wid & 1;           // 2x2 waves, 64x64 each
  const int bm = blockIdx.y * 128, bn = blockIdx.x * 128;
  const int lr = lane & 15, lg = lane >> 4;

  f32x4 acc[4][4] = {};

  for (int k0 = 0; k0 < K; k0 += 32) {
    #pragma unroll
    for (int rnd = 0; rnd < 2; ++rnd) {
      int chunk = rnd * 256 + t;               // 0..511, 16B chunks
      int row = chunk >> 2, c8 = (chunk & 3) * 8;
      GLOAD_LDS(&A[(size_t)(bm + row) * K + k0 + c8], &As[rnd * 64 + wid * 16][0]);
      GLOAD_LDS(&BT[(size_t)(bn + row) * K + k0 + c8], &Bs[rnd * 64 + wid * 16][0]);
    }
    __syncthreads();
    s16x8 af[4], bfr[4];
    #pragma unroll
    for (int i = 0; i < 4; ++i)
      af[i] = *reinterpret_cast<s16x8*>(&As[wm * 64 + i * 16 + lr][lg * 8]);
    #pragma unroll
    for (int j = 0; j < 4; ++j)
      bfr[j] = *reinterpret_cast<s16x8*>(&Bs[wn * 64 + j * 16 + lr][lg * 8]);
    #pragma unroll
    for (int i = 0; i < 4; ++i)
      #pragma unroll
      for (int j = 0; j < 4; ++j)
        acc[i][j] = __builtin_amdgcn_mfma_f32_16x16x32_bf16(af[i], bfr[j], acc[i][j], 0, 0, 0);
    __syncthreads();
  }

  const int r0 = bm + wm * 64, c0 = bn + wn * 64;
  #pragma unroll
  for (int i = 0; i < 4; ++i)
    #pragma unroll
    for (int j = 0; j < 4; ++j)
      #pragma unroll
      for (int r = 0; r < 4; ++r) {
        int row = r0 + i * 16 + lg * 4 + r;
        int col = c0 + j * 16 + lr;
        float v = acc[i][j][r];
        if constexpr (std::is_same<OutT, short>::value)
          C[(size_t)row * N + col] = f2bf(v);
        else
          C[(size_t)row * N + col] = v;
      }
}

// ---------------- flash attention: 4 waves x 32 q-rows, 32x32 MFMA, swapped operands ----
// qkv: [B*T][3072] bf16 (q|k|v); vt: [(b*16+h)*64 + d][2048]; att: [B*T][1024]
// __launch_bounds__(256, 3): VGPR cap ~170 -> prevents accumulator/score spill
// (round-3 build allocated 84 VGPR for ~130 live floats = scratch spill = the 174us)
__global__ __launch_bounds__(256, 3) void attn_kernel(const short* __restrict__ qkv,
                                                      const short* __restrict__ vt,
                                                      short* __restrict__ att) {
  const int T = 2048, C3 = 3072, Cc = 1024;
  const int fid = blockIdx.x;
  const int qb = 15 - (fid >> 6);            // global LPT: all heavy (qb=15) blocks first
  const int bh = fid & 63;
  const int h = bh & 15, b = bh >> 4;
  const int t = threadIdx.x;
  const int w = t >> 6, l = t & 63;
  const int q2 = l & 31, hi = l >> 5;

  __shared__ __align__(16) short Ks[2][64 * 64];   // [key][d], chunk-swizzled
  __shared__ __align__(16) short Vts[2][64 * 64];  // [d][key], chunk-swizzled

  const int qrow_base = qb * 128 + w * 32;
  const int qrow = qrow_base + q2;

  // Q B-fragments (col=lane&31=q, k=d), pre-scaled by 0.125*log2(e)
  const float SC = 0.125f * 1.44269504088896340736f;
  s16x8 aq[4];
  #pragma unroll
  for (int ds = 0; ds < 4; ++ds) {
    s16x8 q = *reinterpret_cast<const s16x8*>(
        qkv + (size_t)(b * T + qrow) * C3 + h * 64 + ds * 16 + hi * 8);
    #pragma unroll
    for (int j = 0; j < 8; ++j) {
      union { float f; unsigned u; } v; v.u = ((unsigned)(unsigned short)q[j]) << 16;
      q[j] = f2bf(v.f * SC);
    }
    aq[ds] = q;
  }

  f32x16 o[2] = {};                  // O^T: [d][q], col=lane&31=q
  float mst = -INFINITY, lst = 0.f;  // scalar per lane (q = q2)

  const int nt = 2 * qb + 2;

  auto stage = [&](int buf, int j0) {
    #pragma unroll
    for (int i = 0; i < 2; ++i) {
      int row = w * 16 + i * 8 + (l >> 3);
      int srcc = (l & 7) ^ (l >> 3);
      GLOAD_LDS(qkv + (size_t)(b * T + j0 + row) * C3 + Cc + h * 64 + srcc * 8,
                &Ks[buf][(w * 16 + i * 8) * 64]);
      GLOAD_LDS(vt + (size_t)(bh * 64 + row) * T + j0 + srcc * 8,
                &Vts[buf][(w * 16 + i * 8) * 64]);
    }
  };

  stage(0, 0);
  for (int tt = 0; tt < nt; ++tt) {
    __syncthreads();
    if (tt + 1 < nt) stage((tt + 1) & 1, (tt + 1) * 64);
    const int j0 = tt * 64;
    if (j0 <= qrow_base + 31) {                 // else fully-masked for this wave
      const short* K_ = Ks[tt & 1];
      const short* V_ = Vts[tt & 1];

      // ---- swapped QK^T: S^T[key][q] ----
      f32x16 st[2];
      __builtin_amdgcn_s_setprio(1);
      #pragma unroll
      for (int kt = 0; kt < 2; ++kt) {
        f32x16 s = {};
        #pragma unroll
        for (int ds = 0; ds < 4; ++ds) {
          int row = kt * 32 + q2;
          s16x8 ak = *reinterpret_cast<const s16x8*>(
              &K_[row * 64 + (((ds * 2 + hi) ^ (row & 7)) * 8)]);
          s = __builtin_amdgcn_mfma_f32_32x32x16_bf16(ak, aq[ds], s, 0, 0, 0);
        }
        st[kt] = s;
      }
      __builtin_amdgcn_s_setprio(0);

      // ---- causal mask (diagonal tiles only) ----
      if (j0 + 63 > qrow_base) {
        #pragma unroll
        for (int kt = 0; kt < 2; ++kt)
          #pragma unroll
          for (int r = 0; r < 16; ++r) {
            int key = j0 + kt * 32 + (r & 3) + 8 * (r >> 2) + 4 * hi;
            if (key > qrow) st[kt][r] = -INFINITY;
          }
      }

      // ---- in-register softmax (exp2 domain) ----
      float a16[16];
      #pragma unroll
      for (int r = 0; r < 16; ++r) a16[r] = fmaxf(st[0][r], st[1][r]);
      #pragma unroll
      for (int r = 0; r < 8; ++r) a16[r] = fmaxf(a16[r], a16[r + 8]);
      #pragma unroll
      for (int r = 0; r < 4; ++r) a16[r] = fmaxf(a16[r], a16[r + 4]);
      float mx = fmaxf(fmaxf(a16[0], a16[1]), fmaxf(a16[2], a16[3]));
      mx = fmaxf(mx, __shfl_xor(mx, 32));
      float mn = fmaxf(mst, mx);
      float corr = exp2f(mst - mn);
      mst = mn;
      #pragma unroll
      for (int kt = 0; kt < 2; ++kt)
        #pragma unroll
        for (int r = 0; r < 16; ++r) st[kt][r] = exp2f(st[kt][r] - mn);
      float sv[16];
      #pragma unroll
      for (int r = 0; r < 16; ++r) sv[r] = st[0][r] + st[1][r];
      #pragma unroll
      for (int r = 0; r < 8; ++r) sv[r] += sv[r + 8];
      #pragma unroll
      for (int r = 0; r < 4; ++r) sv[r] += sv[r + 4];
      float ps = (sv[0] + sv[1]) + (sv[2] + sv[3]);
      ps += __shfl_xor(ps, 32);
      lst = lst * corr + ps;
      #pragma unroll
      for (int dt = 0; dt < 2; ++dt)
        #pragma unroll
        for (int r = 0; r < 16; ++r) o[dt][r] *= corr;

      // ---- repack P^T -> B-fragments (in-register, cvt_pk + shfl exchange) ----
      s16x8 pb[4];
      #pragma unroll
      for (int kt = 0; kt < 2; ++kt)
        #pragma unroll
        for (int s = 0; s < 2; ++s) {
          unsigned w01 = cvt_pk_bf16(st[kt][s * 8 + 0], st[kt][s * 8 + 1]);
          unsigned w23 = cvt_pk_bf16(st[kt][s * 8 + 2], st[kt][s * 8 + 3]);
          unsigned w45 = cvt_pk_bf16(st[kt][s * 8 + 4], st[kt][s * 8 + 5]);
          unsigned w67 = cvt_pk_bf16(st[kt][s * 8 + 6], st[kt][s * 8 + 7]);
          unsigned x01 = (unsigned)__shfl_xor((int)w01, 32);
          unsigned x23 = (unsigned)__shfl_xor((int)w23, 32);
          unsigned x45 = (unsigned)__shfl_xor((int)w45, 32);
          unsigned x67 = (unsigned)__shfl_xor((int)w67, 32);
          u32x4 f;
          f[0] = hi ? x45 : w01;
          f[1] = hi ? x67 : w23;
          f[2] = hi ? w45 : x01;
          f[3] = hi ? w67 : x23;
          pb[kt * 2 + s] = *reinterpret_cast<s16x8*>(&f);
        }

      // ---- swapped PV: O^T[d][q] += V^T[d][k] * P^T[k][q] ----
      __builtin_amdgcn_s_setprio(1);
      #pragma unroll
      for (int dt = 0; dt < 2; ++dt) {
        int row = dt * 32 + q2;
        #pragma unroll
        for (int ks = 0; ks < 4; ++ks) {
          s16x8 av = *reinterpret_cast<const s16x8*>(
              &V_[row * 64 + (((ks * 2 + hi) ^ (row & 7)) * 8)]);
          o[dt] = __builtin_amdgcn_mfma_f32_32x32x16_bf16(av, pb[ks], o[dt], 0, 0, 0);
        }
      }
      __builtin_amdgcn_s_setprio(0);
    }
  }

  // ---- epilogue: O^T -> att[token][C] via swizzled per-wave LDS transpose ----
  __syncthreads();
  u32* osm = reinterpret_cast<u32*>(&Ks[0][0]) + w * 1024;  // 4KB per wave
  float inv = 1.f / lst;
  #pragma unroll
  for (int dt = 0; dt < 2; ++dt)
    #pragma unroll
    for (int p = 0; p < 8; ++p) {
      unsigned pk = ((unsigned)(unsigned short)f2bf(o[dt][2 * p + 1] * inv) << 16)
                  | (unsigned)(unsigned short)f2bf(o[dt][2 * p] * inv);
      int col = dt * 16 + (p >> 1) * 4 + 2 * hi + (p & 1);   // u32 col = d/2
      int chunk = col >> 2, inc = col & 3;
      osm[q2 * 32 + ((chunk ^ (q2 & 7)) * 4) + inc] = pk;
    }
  __syncthreads();
  #pragma unroll
  for (int c = 0; c < 4; ++c) {
    int chunk = hi * 4 + c;
    u32x4 v4 = *reinterpret_cast<u32x4*>(&osm[q2 * 32 + ((chunk ^ (q2 & 7)) * 4)]);
    *reinterpret_cast<u32x4*>(
        att + (size_t)(b * T + qrow_base + q2) * Cc + h * 64 + chunk * 8) = v4;
  }
}

extern "C" void kernel_launch(void* const* d_in, const int* in_sizes, int n_in,
                              void* d_out, int out_size, void* d_ws, size_t ws_size,
                              hipStream_t stream) {
  const float* x     = (const float*)d_in[0];   // [4,2048,1024]
  const float* w_qkv = (const float*)d_in[1];   // [1024,3072]
  const float* w_out = (const float*)d_in[2];   // [1024,1024]
  float* out = (float*)d_out;                   // [4,2048,1024]

  char* ws = (char*)d_ws;
  short* xb    = (short*)(ws);                        // 16,777,216 B (dead after gemm1)
  short* vtb   = (short*)(ws);                        // aliases xb: written after gemm1
  short* wqkvT = (short*)(ws + 16777216);             // 6,291,456
  short* woT   = (short*)(ws + 23068672);             // 2,097,152
  short* qkv   = (short*)(ws + 25165824);             // 50,331,648
  short* att   = (short*)(ws + 75497472);             // 16,777,216  -> total 92.3 MB

  cast_f32_bf16<<<2048, 256, 0, stream>>>(x, xb, (8192 * 1024) / 4);
  transpose_cast<<<dim3(3072 / 32, 1024 / 32), dim3(32, 8), 0, stream>>>(w_qkv, wqkvT, 1024, 3072);
  transpose_cast<<<dim3(1024 / 32, 1024 / 32), dim3(32, 8), 0, stream>>>(w_out, woT, 1024, 1024);

  gemm_bt<short><<<dim3(3072 / 128, 8192 / 128), 256, 0, stream>>>(xb, wqkvT, qkv, 8192, 3072, 1024);
  transpose_v<<<dim3(2048 / 32, 2, 64), dim3(32, 8), 0, stream>>>(qkv, vtb);
  attn_kernel<<<1024, 256, 0, stream>>>(qkv, vtb, att);
  gemm_bt<float><<<dim3(1024 / 128, 8192 / 128), 256, 0, stream>>>(att, woT, out, 8192, 1024, 1024);
}